// Round 4
// baseline (647.233 us; speedup 1.0000x reference)
//
#include <hip/hip_runtime.h>

#define HW (512 * 512)
#define QP 260   // pitch (floats): >=256, %32==4 -> kv-phase b128 reads hit all 32 banks once

typedef __bf16 bf16;
typedef __attribute__((ext_vector_type(8))) __bf16 bf16x8;
typedef __attribute__((ext_vector_type(4))) float f32x4;

__device__ __forceinline__ void cvt_split(float f, bf16& h, bf16& l) {
    h = (bf16)f;
    l = (bf16)(f - (float)h);
}

__global__ __launch_bounds__(256, 5) void lwmsa_kernel(
    const float* __restrict__ x,
    const float* __restrict__ w,
    float* __restrict__ out)
{
    const int win  = blockIdx.x;       // 0..4095
    const int b    = win >> 10;
    const int wrow = (win >> 5) & 31;
    const int wcol = win & 31;
    const int n    = threadIdx.x;      // 0..255 = pixel in window
    const int lane = n & 63;
    const int wvid = n >> 6;           // wave 0..3
    const int c16  = lane & 15;        // fragment N-col / row index
    const int q4   = lane >> 4;        // fragment quarter

    const int base = b * (64 * HW) + (wrow * 16 + (n >> 4)) * 512 + wcol * 16 + (n & 15);
    const int xwin = b * (64 * HW) + (wrow * 16) * 512 + wcol * 16;   // window origin

    __shared__ float qk[24 * QP];      // ONE head: q rows 0-7, k 8-15, v 16-23, [row][px]
    __shared__ float kvp[4 * 64];
    __shared__ float kv_s[64];
    __shared__ float tp[4];

    // ---- A-fragments (X), hi/lo, straight from global into registers ----
    bf16x8 ah[2][4], al[2][4];
    #pragma unroll
    for (int ks = 0; ks < 2; ++ks)
        #pragma unroll
        for (int mt = 0; mt < 4; ++mt) {
            const int row = wvid * 4 + mt;
            const float* xp = x + xwin + row * 512 + c16 + (ks * 32 + q4 * 8) * HW;
            #pragma unroll
            for (int j = 0; j < 8; ++j) {
                bf16 h, l;
                cvt_split(xp[j * HW], h, l);
                ah[ks][mt][j] = h;
                al[ks][mt][j] = l;
            }
        }

    float feat[8];
    #pragma unroll
    for (int d = 0; d < 8; ++d) feat[d] = 0.f;

    for (int g = 0; g < 4; ++g) {      // head pair (2g, 2g+1)
        // ---- MFMA: D[px][pairrow] = X . W^T, 48 rows, K=64, 3-term split ----
        f32x4 acc[4][3];
        #pragma unroll
        for (int mt = 0; mt < 4; ++mt)
            #pragma unroll
            for (int nt = 0; nt < 3; ++nt)
                acc[mt][nt] = (f32x4){0.f, 0.f, 0.f, 0.f};

        #pragma unroll
        for (int ks = 0; ks < 2; ++ks) {
            #pragma unroll
            for (int nt = 0; nt < 3; ++nt) {
                const int ml   = nt * 16 + c16;                 // 0..47 pair-local row
                const int head = 2 * g + (ml >= 24 ? 1 : 0);
                const int mm   = (ml >= 24) ? ml - 24 : ml;
                const int grow = (mm >> 3) * 64 + head * 8 + (mm & 7);  // row in w[192][64]
                const float4* wp = (const float4*)(w + grow * 64 + ks * 32 + q4 * 8);
                const float4 wa = wp[0];
                const float4 wb = wp[1];
                bf16x8 bh, bl;
                bf16 h, l;
                cvt_split(wa.x, h, l); bh[0] = h; bl[0] = l;
                cvt_split(wa.y, h, l); bh[1] = h; bl[1] = l;
                cvt_split(wa.z, h, l); bh[2] = h; bl[2] = l;
                cvt_split(wa.w, h, l); bh[3] = h; bl[3] = l;
                cvt_split(wb.x, h, l); bh[4] = h; bl[4] = l;
                cvt_split(wb.y, h, l); bh[5] = h; bl[5] = l;
                cvt_split(wb.z, h, l); bh[6] = h; bl[6] = l;
                cvt_split(wb.w, h, l); bh[7] = h; bl[7] = l;
                #pragma unroll
                for (int mt = 0; mt < 4; ++mt) {
                    acc[mt][nt] = __builtin_amdgcn_mfma_f32_16x16x32_bf16(ah[ks][mt], bh, acc[mt][nt], 0, 0, 0);
                    acc[mt][nt] = __builtin_amdgcn_mfma_f32_16x16x32_bf16(al[ks][mt], bh, acc[mt][nt], 0, 0, 0);
                    acc[mt][nt] = __builtin_amdgcn_mfma_f32_16x16x32_bf16(ah[ks][mt], bl, acc[mt][nt], 0, 0, 0);
                }
            }
        }

        // ---- serial per-head math; stage only this head's 24 rows ----
        #pragma unroll
        for (int lh = 0; lh < 2; ++lh) {

            __syncthreads();  // S0: all prev-head qk/kv_s/tp/kvp consumers done

            // stage head lh: local rows 0-7=q, 8-15=k, 16-23=v
            // pair-row ml = nt*16 + c16; head lh owns ml in [lh*24, lh*24+24)
            if (lh == 0) {
                #pragma unroll
                for (int mt = 0; mt < 4; ++mt) {
                    const int px = (wvid * 4 + mt) * 16 + q4 * 4;
                    *(float4*)&qk[c16 * QP + px] = *(float4*)&acc[mt][0];
                }
                if (c16 < 8) {
                    #pragma unroll
                    for (int mt = 0; mt < 4; ++mt) {
                        const int px = (wvid * 4 + mt) * 16 + q4 * 4;
                        *(float4*)&qk[(16 + c16) * QP + px] = *(float4*)&acc[mt][1];
                    }
                }
            } else {
                if (c16 >= 8) {
                    #pragma unroll
                    for (int mt = 0; mt < 4; ++mt) {
                        const int px = (wvid * 4 + mt) * 16 + q4 * 4;
                        *(float4*)&qk[(c16 - 8) * QP + px] = *(float4*)&acc[mt][1];
                    }
                }
                #pragma unroll
                for (int mt = 0; mt < 4; ++mt) {
                    const int px = (wvid * 4 + mt) * 16 + q4 * 4;
                    *(float4*)&qk[(8 + c16) * QP + px] = *(float4*)&acc[mt][2];
                }
            }

            __syncthreads();  // S1: staging visible

            float aq[8], ak[8], av[8];
            #pragma unroll
            for (int d = 0; d < 8; ++d) {
                aq[d] = qk[d * QP + n]        + feat[d];
                ak[d] = qk[(8 + d) * QP + n]  + feat[d];
                av[d] = qk[(16 + d) * QP + n] + feat[d];
            }

            float qf[8], kf[8];
            float Sq = 0.f, tpart = 0.f;
            #pragma unroll
            for (int d = 0; d < 8; ++d) {
                qf[d] = aq[d] > 0.f ? aq[d] + 1.f : __expf(aq[d]);
                kf[d] = ak[d] > 0.f ? ak[d] + 1.f : __expf(ak[d]);
                Sq    += qf[d];
                tpart += kf[d];
            }

            // overwrite k,v rows (own column only — no cross-thread hazard)
            #pragma unroll
            for (int d = 0; d < 8; ++d) {
                qk[(8 + d) * QP + n]  = kf[d];
                qk[(16 + d) * QP + n] = av[d];
            }

            #pragma unroll
            for (int off = 1; off < 64; off <<= 1)
                tpart += __shfl_xor(tpart, off, 64);
            if (lane == 0) tp[wvid] = tpart;

            __syncthreads();  // S2: kf/v/tp staged

            {
                const float4* kr = (const float4*)(qk + (8 + (lane >> 3)) * QP + wvid * 64);
                const float4* vr = (const float4*)(qk + (16 + (lane & 7)) * QP + wvid * 64);
                float s0 = 0.f, s1 = 0.f, s2 = 0.f, s3 = 0.f;
                #pragma unroll
                for (int j = 0; j < 16; ++j) {
                    const float4 kk = kr[j];
                    const float4 vv = vr[j];
                    s0 = fmaf(kk.x, vv.x, s0);
                    s1 = fmaf(kk.y, vv.y, s1);
                    s2 = fmaf(kk.z, vv.z, s2);
                    s3 = fmaf(kk.w, vv.w, s3);
                }
                kvp[wvid * 64 + lane] = (s0 + s1) + (s2 + s3);
            }

            __syncthreads();  // S3

            if (n < 64)
                kv_s[n] = (kvp[n] + kvp[64 + n]) + (kvp[128 + n] + kvp[192 + n]);

            __syncthreads();  // S4

            const float T  = ((tp[0] + tp[1]) + (tp[2] + tp[3])) + 8.0f * 1e-6f;
            const float zi = 1.0f / (Sq * T);

            #pragma unroll
            for (int d = 0; d < 8; ++d) feat[d] = 0.f;
            #pragma unroll
            for (int d = 0; d < 8; ++d) {
                const float qd = qf[d];
                const float4 a  = ((const float4*)(kv_s + d * 8))[0];
                const float4 bb = ((const float4*)(kv_s + d * 8))[1];
                feat[0] = fmaf(qd, a.x,  feat[0]);
                feat[1] = fmaf(qd, a.y,  feat[1]);
                feat[2] = fmaf(qd, a.z,  feat[2]);
                feat[3] = fmaf(qd, a.w,  feat[3]);
                feat[4] = fmaf(qd, bb.x, feat[4]);
                feat[5] = fmaf(qd, bb.y, feat[5]);
                feat[6] = fmaf(qd, bb.z, feat[6]);
                feat[7] = fmaf(qd, bb.w, feat[7]);
            }

            const int ch0 = (2 * g + lh) * 8;
            #pragma unroll
            for (int d = 0; d < 8; ++d) {
                feat[d] *= zi;
                out[base + (ch0 + d) * HW] = feat[d];
            }
        }
    }
}

extern "C" void kernel_launch(void* const* d_in, const int* in_sizes, int n_in,
                              void* d_out, int out_size, void* d_ws, size_t ws_size,
                              hipStream_t stream) {
    const float* x  = (const float*)d_in[0];
    const float* w  = (const float*)d_in[1];
    float* out      = (float*)d_out;
    lwmsa_kernel<<<dim3(4096), dim3(256), 0, stream>>>(x, w, out);
}

// Round 5
// 437.910 us; speedup vs baseline: 1.4780x; 1.4780x over previous
//
#include <hip/hip_runtime.h>

#define HW (512 * 512)
#define QP 260   // pitch (floats): >=256, %32==4 -> kv-phase b128 reads hit all 32 banks once

typedef __bf16 bf16;
typedef __attribute__((ext_vector_type(8))) __bf16 bf16x8;
typedef __attribute__((ext_vector_type(4))) float f32x4;

__device__ __forceinline__ void cvt_split(float f, bf16& h, bf16& l) {
    h = (bf16)f;
    l = (bf16)(f - (float)h);
}

// (256,4): VGPR cap 128 > natural ~88 (R3) -> no spill/remat; LDS 26.6KB -> 4 blocks/CU.
// (256,5) in R4 capped VGPR at ~96 -> compiler rematerialized X per head-pair: FETCH 5x, 1.9x slower.
__global__ __launch_bounds__(256, 4) void lwmsa_kernel(
    const float* __restrict__ x,
    const float* __restrict__ w,
    float* __restrict__ out)
{
    const int win  = blockIdx.x;       // 0..4095
    const int b    = win >> 10;
    const int wrow = (win >> 5) & 31;
    const int wcol = win & 31;
    const int n    = threadIdx.x;      // 0..255 = pixel in window
    const int lane = n & 63;
    const int wvid = n >> 6;           // wave 0..3
    const int c16  = lane & 15;        // fragment N-col / row index
    const int q4   = lane >> 4;        // fragment quarter

    const int base = b * (64 * HW) + (wrow * 16 + (n >> 4)) * 512 + wcol * 16 + (n & 15);
    const int xwin = b * (64 * HW) + (wrow * 16) * 512 + wcol * 16;   // window origin

    __shared__ float qk[24 * QP];      // ONE head: q rows 0-7, k 8-15, v 16-23, [row][px]
    __shared__ float kvp[4 * 64];
    __shared__ float kv_s[64];
    __shared__ float tp[4];

    // ---- A-fragments (X), hi/lo, straight from global into registers ----
    bf16x8 ah[2][4], al[2][4];
    #pragma unroll
    for (int ks = 0; ks < 2; ++ks)
        #pragma unroll
        for (int mt = 0; mt < 4; ++mt) {
            const int row = wvid * 4 + mt;
            const float* xp = x + xwin + row * 512 + c16 + (ks * 32 + q4 * 8) * HW;
            #pragma unroll
            for (int j = 0; j < 8; ++j) {
                bf16 h, l;
                cvt_split(xp[j * HW], h, l);
                ah[ks][mt][j] = h;
                al[ks][mt][j] = l;
            }
        }

    float feat[8];
    #pragma unroll
    for (int d = 0; d < 8; ++d) feat[d] = 0.f;

    for (int g = 0; g < 4; ++g) {      // head pair (2g, 2g+1)
        // ---- MFMA: D[px][pairrow] = X . W^T, 48 rows, K=64, 3-term split ----
        f32x4 acc[4][3];
        #pragma unroll
        for (int mt = 0; mt < 4; ++mt)
            #pragma unroll
            for (int nt = 0; nt < 3; ++nt)
                acc[mt][nt] = (f32x4){0.f, 0.f, 0.f, 0.f};

        #pragma unroll
        for (int ks = 0; ks < 2; ++ks) {
            #pragma unroll
            for (int nt = 0; nt < 3; ++nt) {
                const int ml   = nt * 16 + c16;                 // 0..47 pair-local row
                const int head = 2 * g + (ml >= 24 ? 1 : 0);
                const int mm   = (ml >= 24) ? ml - 24 : ml;
                const int grow = (mm >> 3) * 64 + head * 8 + (mm & 7);  // row in w[192][64]
                const float4* wp = (const float4*)(w + grow * 64 + ks * 32 + q4 * 8);
                const float4 wa = wp[0];
                const float4 wb = wp[1];
                bf16x8 bh, bl;
                bf16 h, l;
                cvt_split(wa.x, h, l); bh[0] = h; bl[0] = l;
                cvt_split(wa.y, h, l); bh[1] = h; bl[1] = l;
                cvt_split(wa.z, h, l); bh[2] = h; bl[2] = l;
                cvt_split(wa.w, h, l); bh[3] = h; bl[3] = l;
                cvt_split(wb.x, h, l); bh[4] = h; bl[4] = l;
                cvt_split(wb.y, h, l); bh[5] = h; bl[5] = l;
                cvt_split(wb.z, h, l); bh[6] = h; bl[6] = l;
                cvt_split(wb.w, h, l); bh[7] = h; bl[7] = l;
                #pragma unroll
                for (int mt = 0; mt < 4; ++mt) {
                    acc[mt][nt] = __builtin_amdgcn_mfma_f32_16x16x32_bf16(ah[ks][mt], bh, acc[mt][nt], 0, 0, 0);
                    acc[mt][nt] = __builtin_amdgcn_mfma_f32_16x16x32_bf16(al[ks][mt], bh, acc[mt][nt], 0, 0, 0);
                    acc[mt][nt] = __builtin_amdgcn_mfma_f32_16x16x32_bf16(ah[ks][mt], bl, acc[mt][nt], 0, 0, 0);
                }
            }
        }

        // ---- serial per-head math; stage only this head's 24 rows ----
        #pragma unroll
        for (int lh = 0; lh < 2; ++lh) {

            __syncthreads();  // S0: all prev-head qk/kv_s/tp/kvp consumers done

            // stage head lh: local rows 0-7=q, 8-15=k, 16-23=v
            // pair-row ml = nt*16 + c16; head lh owns ml in [lh*24, lh*24+24)
            if (lh == 0) {
                #pragma unroll
                for (int mt = 0; mt < 4; ++mt) {
                    const int px = (wvid * 4 + mt) * 16 + q4 * 4;
                    *(float4*)&qk[c16 * QP + px] = *(float4*)&acc[mt][0];
                }
                if (c16 < 8) {
                    #pragma unroll
                    for (int mt = 0; mt < 4; ++mt) {
                        const int px = (wvid * 4 + mt) * 16 + q4 * 4;
                        *(float4*)&qk[(16 + c16) * QP + px] = *(float4*)&acc[mt][1];
                    }
                }
            } else {
                if (c16 >= 8) {
                    #pragma unroll
                    for (int mt = 0; mt < 4; ++mt) {
                        const int px = (wvid * 4 + mt) * 16 + q4 * 4;
                        *(float4*)&qk[(c16 - 8) * QP + px] = *(float4*)&acc[mt][1];
                    }
                }
                #pragma unroll
                for (int mt = 0; mt < 4; ++mt) {
                    const int px = (wvid * 4 + mt) * 16 + q4 * 4;
                    *(float4*)&qk[(8 + c16) * QP + px] = *(float4*)&acc[mt][2];
                }
            }

            __syncthreads();  // S1: staging visible

            float aq[8], ak[8], av[8];
            #pragma unroll
            for (int d = 0; d < 8; ++d) {
                aq[d] = qk[d * QP + n]        + feat[d];
                ak[d] = qk[(8 + d) * QP + n]  + feat[d];
                av[d] = qk[(16 + d) * QP + n] + feat[d];
            }

            float qf[8], kf[8];
            float Sq = 0.f, tpart = 0.f;
            #pragma unroll
            for (int d = 0; d < 8; ++d) {
                qf[d] = aq[d] > 0.f ? aq[d] + 1.f : __expf(aq[d]);
                kf[d] = ak[d] > 0.f ? ak[d] + 1.f : __expf(ak[d]);
                Sq    += qf[d];
                tpart += kf[d];
            }

            // overwrite k,v rows (own column only — no cross-thread hazard)
            #pragma unroll
            for (int d = 0; d < 8; ++d) {
                qk[(8 + d) * QP + n]  = kf[d];
                qk[(16 + d) * QP + n] = av[d];
            }

            #pragma unroll
            for (int off = 1; off < 64; off <<= 1)
                tpart += __shfl_xor(tpart, off, 64);
            if (lane == 0) tp[wvid] = tpart;

            __syncthreads();  // S2: kf/v/tp staged

            {
                const float4* kr = (const float4*)(qk + (8 + (lane >> 3)) * QP + wvid * 64);
                const float4* vr = (const float4*)(qk + (16 + (lane & 7)) * QP + wvid * 64);
                float s0 = 0.f, s1 = 0.f, s2 = 0.f, s3 = 0.f;
                #pragma unroll
                for (int j = 0; j < 16; ++j) {
                    const float4 kk = kr[j];
                    const float4 vv = vr[j];
                    s0 = fmaf(kk.x, vv.x, s0);
                    s1 = fmaf(kk.y, vv.y, s1);
                    s2 = fmaf(kk.z, vv.z, s2);
                    s3 = fmaf(kk.w, vv.w, s3);
                }
                kvp[wvid * 64 + lane] = (s0 + s1) + (s2 + s3);
            }

            __syncthreads();  // S3

            if (n < 64)
                kv_s[n] = (kvp[n] + kvp[64 + n]) + (kvp[128 + n] + kvp[192 + n]);

            __syncthreads();  // S4

            const float T  = ((tp[0] + tp[1]) + (tp[2] + tp[3])) + 8.0f * 1e-6f;
            const float zi = 1.0f / (Sq * T);

            #pragma unroll
            for (int d = 0; d < 8; ++d) feat[d] = 0.f;
            #pragma unroll
            for (int d = 0; d < 8; ++d) {
                const float qd = qf[d];
                const float4 a  = ((const float4*)(kv_s + d * 8))[0];
                const float4 bb = ((const float4*)(kv_s + d * 8))[1];
                feat[0] = fmaf(qd, a.x,  feat[0]);
                feat[1] = fmaf(qd, a.y,  feat[1]);
                feat[2] = fmaf(qd, a.z,  feat[2]);
                feat[3] = fmaf(qd, a.w,  feat[3]);
                feat[4] = fmaf(qd, bb.x, feat[4]);
                feat[5] = fmaf(qd, bb.y, feat[5]);
                feat[6] = fmaf(qd, bb.z, feat[6]);
                feat[7] = fmaf(qd, bb.w, feat[7]);
            }

            const int ch0 = (2 * g + lh) * 8;
            #pragma unroll
            for (int d = 0; d < 8; ++d) {
                feat[d] *= zi;
                out[base + (ch0 + d) * HW] = feat[d];
            }
        }
    }
}

extern "C" void kernel_launch(void* const* d_in, const int* in_sizes, int n_in,
                              void* d_out, int out_size, void* d_ws, size_t ws_size,
                              hipStream_t stream) {
    const float* x  = (const float*)d_in[0];
    const float* w  = (const float*)d_in[1];
    float* out      = (float*)d_out;
    lwmsa_kernel<<<dim3(4096), dim3(256), 0, stream>>>(x, w, out);
}

// Round 6
// 299.973 us; speedup vs baseline: 2.1576x; 1.4598x over previous
//
#include <hip/hip_runtime.h>

#define HW (512 * 512)
#define QP 260   // pitch (floats): >=256, %32==4 -> kv-phase b128 reads hit all 32 banks once

typedef __bf16 bf16;
typedef __attribute__((ext_vector_type(8))) __bf16 bf16x8;
typedef __attribute__((ext_vector_type(4))) float f32x4;

__device__ __forceinline__ void cvt_split(float f, bf16& h, bf16& l) {
    h = (bf16)f;
    l = (bf16)(f - (float)h);
}

// (256,2): VGPR cap 256 >> natural ~88 -> no spill/remat (R4's (256,5) and R5's (256,4)
// both forced VGPR caps that produced scratch traffic: WRITE 2.6x, FETCH 3.3x).
// Occupancy then comes from the pool: floor(512/88)=5 waves/SIMD -> 5 blocks/CU;
// LDS 26.6KB admits 6. Expect ~55-62% occupancy with exact FETCH/WRITE.
__global__ __launch_bounds__(256, 2) void lwmsa_kernel(
    const float* __restrict__ x,
    const float* __restrict__ w,
    float* __restrict__ out)
{
    const int win  = blockIdx.x;       // 0..4095
    const int b    = win >> 10;
    const int wrow = (win >> 5) & 31;
    const int wcol = win & 31;
    const int n    = threadIdx.x;      // 0..255 = pixel in window
    const int lane = n & 63;
    const int wvid = n >> 6;           // wave 0..3
    const int c16  = lane & 15;        // fragment N-col / row index
    const int q4   = lane >> 4;        // fragment quarter

    const int base = b * (64 * HW) + (wrow * 16 + (n >> 4)) * 512 + wcol * 16 + (n & 15);
    const int xwin = b * (64 * HW) + (wrow * 16) * 512 + wcol * 16;   // window origin

    __shared__ float qk[24 * QP];      // ONE head: q rows 0-7, k 8-15, v 16-23, [row][px]
    __shared__ float kvp[4 * 64];
    __shared__ float kv_s[64];
    __shared__ float tp[4];

    // ---- A-fragments (X), hi/lo, straight from global into registers ----
    bf16x8 ah[2][4], al[2][4];
    #pragma unroll
    for (int ks = 0; ks < 2; ++ks)
        #pragma unroll
        for (int mt = 0; mt < 4; ++mt) {
            const int row = wvid * 4 + mt;
            const float* xp = x + xwin + row * 512 + c16 + (ks * 32 + q4 * 8) * HW;
            #pragma unroll
            for (int j = 0; j < 8; ++j) {
                bf16 h, l;
                cvt_split(xp[j * HW], h, l);
                ah[ks][mt][j] = h;
                al[ks][mt][j] = l;
            }
        }

    float feat[8];
    #pragma unroll
    for (int d = 0; d < 8; ++d) feat[d] = 0.f;

    for (int g = 0; g < 4; ++g) {      // head pair (2g, 2g+1)
        // ---- MFMA: D[px][pairrow] = X . W^T, 48 rows, K=64, 3-term split ----
        f32x4 acc[4][3];
        #pragma unroll
        for (int mt = 0; mt < 4; ++mt)
            #pragma unroll
            for (int nt = 0; nt < 3; ++nt)
                acc[mt][nt] = (f32x4){0.f, 0.f, 0.f, 0.f};

        #pragma unroll
        for (int ks = 0; ks < 2; ++ks) {
            #pragma unroll
            for (int nt = 0; nt < 3; ++nt) {
                const int ml   = nt * 16 + c16;                 // 0..47 pair-local row
                const int head = 2 * g + (ml >= 24 ? 1 : 0);
                const int mm   = (ml >= 24) ? ml - 24 : ml;
                const int grow = (mm >> 3) * 64 + head * 8 + (mm & 7);  // row in w[192][64]
                const float4* wp = (const float4*)(w + grow * 64 + ks * 32 + q4 * 8);
                const float4 wa = wp[0];
                const float4 wb = wp[1];
                bf16x8 bh, bl;
                bf16 h, l;
                cvt_split(wa.x, h, l); bh[0] = h; bl[0] = l;
                cvt_split(wa.y, h, l); bh[1] = h; bl[1] = l;
                cvt_split(wa.z, h, l); bh[2] = h; bl[2] = l;
                cvt_split(wa.w, h, l); bh[3] = h; bl[3] = l;
                cvt_split(wb.x, h, l); bh[4] = h; bl[4] = l;
                cvt_split(wb.y, h, l); bh[5] = h; bl[5] = l;
                cvt_split(wb.z, h, l); bh[6] = h; bl[6] = l;
                cvt_split(wb.w, h, l); bh[7] = h; bl[7] = l;
                #pragma unroll
                for (int mt = 0; mt < 4; ++mt) {
                    acc[mt][nt] = __builtin_amdgcn_mfma_f32_16x16x32_bf16(ah[ks][mt], bh, acc[mt][nt], 0, 0, 0);
                    acc[mt][nt] = __builtin_amdgcn_mfma_f32_16x16x32_bf16(al[ks][mt], bh, acc[mt][nt], 0, 0, 0);
                    acc[mt][nt] = __builtin_amdgcn_mfma_f32_16x16x32_bf16(ah[ks][mt], bl, acc[mt][nt], 0, 0, 0);
                }
            }
        }

        // ---- serial per-head math; stage only this head's 24 rows ----
        #pragma unroll
        for (int lh = 0; lh < 2; ++lh) {

            __syncthreads();  // S0: all prev-head qk/kv_s/tp/kvp consumers done

            // stage head lh: local rows 0-7=q, 8-15=k, 16-23=v
            // pair-row ml = nt*16 + c16; head lh owns ml in [lh*24, lh*24+24)
            if (lh == 0) {
                #pragma unroll
                for (int mt = 0; mt < 4; ++mt) {
                    const int px = (wvid * 4 + mt) * 16 + q4 * 4;
                    *(float4*)&qk[c16 * QP + px] = *(float4*)&acc[mt][0];
                }
                if (c16 < 8) {
                    #pragma unroll
                    for (int mt = 0; mt < 4; ++mt) {
                        const int px = (wvid * 4 + mt) * 16 + q4 * 4;
                        *(float4*)&qk[(16 + c16) * QP + px] = *(float4*)&acc[mt][1];
                    }
                }
            } else {
                if (c16 >= 8) {
                    #pragma unroll
                    for (int mt = 0; mt < 4; ++mt) {
                        const int px = (wvid * 4 + mt) * 16 + q4 * 4;
                        *(float4*)&qk[(c16 - 8) * QP + px] = *(float4*)&acc[mt][1];
                    }
                }
                #pragma unroll
                for (int mt = 0; mt < 4; ++mt) {
                    const int px = (wvid * 4 + mt) * 16 + q4 * 4;
                    *(float4*)&qk[(8 + c16) * QP + px] = *(float4*)&acc[mt][2];
                }
            }

            __syncthreads();  // S1: staging visible

            float aq[8], ak[8], av[8];
            #pragma unroll
            for (int d = 0; d < 8; ++d) {
                aq[d] = qk[d * QP + n]        + feat[d];
                ak[d] = qk[(8 + d) * QP + n]  + feat[d];
                av[d] = qk[(16 + d) * QP + n] + feat[d];
            }

            float qf[8], kf[8];
            float Sq = 0.f, tpart = 0.f;
            #pragma unroll
            for (int d = 0; d < 8; ++d) {
                qf[d] = aq[d] > 0.f ? aq[d] + 1.f : __expf(aq[d]);
                kf[d] = ak[d] > 0.f ? ak[d] + 1.f : __expf(ak[d]);
                Sq    += qf[d];
                tpart += kf[d];
            }

            // overwrite k,v rows (own column only — no cross-thread hazard)
            #pragma unroll
            for (int d = 0; d < 8; ++d) {
                qk[(8 + d) * QP + n]  = kf[d];
                qk[(16 + d) * QP + n] = av[d];
            }

            #pragma unroll
            for (int off = 1; off < 64; off <<= 1)
                tpart += __shfl_xor(tpart, off, 64);
            if (lane == 0) tp[wvid] = tpart;

            __syncthreads();  // S2: kf/v/tp staged

            {
                const float4* kr = (const float4*)(qk + (8 + (lane >> 3)) * QP + wvid * 64);
                const float4* vr = (const float4*)(qk + (16 + (lane & 7)) * QP + wvid * 64);
                float s0 = 0.f, s1 = 0.f, s2 = 0.f, s3 = 0.f;
                #pragma unroll
                for (int j = 0; j < 16; ++j) {
                    const float4 kk = kr[j];
                    const float4 vv = vr[j];
                    s0 = fmaf(kk.x, vv.x, s0);
                    s1 = fmaf(kk.y, vv.y, s1);
                    s2 = fmaf(kk.z, vv.z, s2);
                    s3 = fmaf(kk.w, vv.w, s3);
                }
                kvp[wvid * 64 + lane] = (s0 + s1) + (s2 + s3);
            }

            __syncthreads();  // S3

            if (n < 64)
                kv_s[n] = (kvp[n] + kvp[64 + n]) + (kvp[128 + n] + kvp[192 + n]);

            __syncthreads();  // S4

            const float T  = ((tp[0] + tp[1]) + (tp[2] + tp[3])) + 8.0f * 1e-6f;
            const float zi = 1.0f / (Sq * T);

            #pragma unroll
            for (int d = 0; d < 8; ++d) feat[d] = 0.f;
            #pragma unroll
            for (int d = 0; d < 8; ++d) {
                const float qd = qf[d];
                const float4 a  = ((const float4*)(kv_s + d * 8))[0];
                const float4 bb = ((const float4*)(kv_s + d * 8))[1];
                feat[0] = fmaf(qd, a.x,  feat[0]);
                feat[1] = fmaf(qd, a.y,  feat[1]);
                feat[2] = fmaf(qd, a.z,  feat[2]);
                feat[3] = fmaf(qd, a.w,  feat[3]);
                feat[4] = fmaf(qd, bb.x, feat[4]);
                feat[5] = fmaf(qd, bb.y, feat[5]);
                feat[6] = fmaf(qd, bb.z, feat[6]);
                feat[7] = fmaf(qd, bb.w, feat[7]);
            }

            const int ch0 = (2 * g + lh) * 8;
            #pragma unroll
            for (int d = 0; d < 8; ++d) {
                feat[d] *= zi;
                out[base + (ch0 + d) * HW] = feat[d];
            }
        }
    }
}

extern "C" void kernel_launch(void* const* d_in, const int* in_sizes, int n_in,
                              void* d_out, int out_size, void* d_ws, size_t ws_size,
                              hipStream_t stream) {
    const float* x  = (const float*)d_in[0];
    const float* w  = (const float*)d_in[1];
    float* out      = (float*)d_out;
    lwmsa_kernel<<<dim3(4096), dim3(256), 0, stream>>>(x, w, out);
}

// Round 7
// 277.171 us; speedup vs baseline: 2.3351x; 1.0823x over previous
//
#include <hip/hip_runtime.h>

#define HW (512 * 512)
#define QP 260   // pitch (floats): >=256, %32==4 -> staggered banks for row-strided reads

typedef __bf16 bf16;
typedef __attribute__((ext_vector_type(8))) __bf16 bf16x8;
typedef __attribute__((ext_vector_type(4))) float f32x4;

__device__ __forceinline__ void cvt_split(float f, bf16& h, bf16& l) {
    h = (bf16)f;
    l = (bf16)(f - (float)h);
}

// Occupancy law measured R3-R6: waves/SIMD = 512 / quantum, quantum = roundup(VGPR+AGPR
// to 64/128/256). R6: 104+48=152 -> 256 -> 2 waves/SIMD (22%). This version: per-head
// MFMA (acc[4][2]=32 AGPRs, dead during serial phase) to target <=128 total. NO cap:
// R4 (256,5) and R5 (256,4) both proved forced caps => remat/spill (FETCH 3-5x).
// Barrier schedule: 3/head (S2 kf/av/tp visible; S3 kvp visible; S4 kv_s + next head's
// projections visible). MFMA(h+1)+stage runs in the S3->S4 slot, overlapped with the
// n<64 reduce. tp is parity-buffered: head h reads tp[h&1] after S4 while head h+1
// writes tp[(h+1)&1] before its S2.
__global__ __launch_bounds__(256, 2) void lwmsa_kernel(
    const float* __restrict__ x,
    const float* __restrict__ w,
    float* __restrict__ out)
{
    const int win  = blockIdx.x;       // 0..4095
    const int b    = win >> 10;
    const int wrow = (win >> 5) & 31;
    const int wcol = win & 31;
    const int n    = threadIdx.x;      // 0..255 = pixel in window
    const int lane = n & 63;
    const int wvid = n >> 6;           // wave 0..3
    const int c16  = lane & 15;
    const int q4   = lane >> 4;

    const int base = b * (64 * HW) + (wrow * 16 + (n >> 4)) * 512 + wcol * 16 + (n & 15);
    const int xwin = b * (64 * HW) + (wrow * 16) * 512 + wcol * 16;

    __shared__ float qk[24 * QP];      // current head: q rows 0-7, k 8-15, v 16-23
    __shared__ float kvp[4 * 64];
    __shared__ float kv_s[64];
    __shared__ float tp[2][4];         // parity-buffered k-sum partials

    // ---- A-fragments (X), hi/lo, global -> registers, persistent across all heads ----
    bf16x8 ah[2][4], al[2][4];
    #pragma unroll
    for (int ks = 0; ks < 2; ++ks)
        #pragma unroll
        for (int mt = 0; mt < 4; ++mt) {
            const int row = wvid * 4 + mt;
            const float* xp = x + xwin + row * 512 + c16 + (ks * 32 + q4 * 8) * HW;
            #pragma unroll
            for (int j = 0; j < 8; ++j) {
                bf16 h, l;
                cvt_split(xp[j * HW], h, l);
                ah[ks][mt][j] = h;
                al[ks][mt][j] = l;
            }
        }

    // ---- per-head MFMA + stage: 24 rows (q0-7,k8-15,v16-23) of head hh ----
    auto mfma_stage = [&](int hh) {
        f32x4 acc[4][2];
        #pragma unroll
        for (int mt = 0; mt < 4; ++mt)
            #pragma unroll
            for (int nt = 0; nt < 2; ++nt)
                acc[mt][nt] = (f32x4){0.f, 0.f, 0.f, 0.f};

        #pragma unroll
        for (int ks = 0; ks < 2; ++ks) {
            #pragma unroll
            for (int nt = 0; nt < 2; ++nt) {
                const int ml   = nt * 16 + c16;                 // 0..31; valid < 24
                const int grow = (ml < 24) ? ((ml >> 3) * 64 + hh * 8 + (ml & 7))
                                           : (hh * 8);          // in-bounds dummy
                const float4* wp = (const float4*)(w + grow * 64 + ks * 32 + q4 * 8);
                const float4 wa = wp[0];
                const float4 wb = wp[1];
                bf16x8 bh, bl;
                bf16 h, l;
                cvt_split(wa.x, h, l); bh[0] = h; bl[0] = l;
                cvt_split(wa.y, h, l); bh[1] = h; bl[1] = l;
                cvt_split(wa.z, h, l); bh[2] = h; bl[2] = l;
                cvt_split(wa.w, h, l); bh[3] = h; bl[3] = l;
                cvt_split(wb.x, h, l); bh[4] = h; bl[4] = l;
                cvt_split(wb.y, h, l); bh[5] = h; bl[5] = l;
                cvt_split(wb.z, h, l); bh[6] = h; bl[6] = l;
                cvt_split(wb.w, h, l); bh[7] = h; bl[7] = l;
                #pragma unroll
                for (int mt = 0; mt < 4; ++mt) {
                    acc[mt][nt] = __builtin_amdgcn_mfma_f32_16x16x32_bf16(ah[ks][mt], bh, acc[mt][nt], 0, 0, 0);
                    acc[mt][nt] = __builtin_amdgcn_mfma_f32_16x16x32_bf16(al[ks][mt], bh, acc[mt][nt], 0, 0, 0);
                    acc[mt][nt] = __builtin_amdgcn_mfma_f32_16x16x32_bf16(ah[ks][mt], bl, acc[mt][nt], 0, 0, 0);
                }
            }
        }

        // D: lane holds qkv-row ml=nt*16+c16 at px=(wvid*4+mt)*16+q4*4+reg
        #pragma unroll
        for (int nt = 0; nt < 2; ++nt) {
            const int ml = nt * 16 + c16;
            if (ml < 24) {
                #pragma unroll
                for (int mt = 0; mt < 4; ++mt) {
                    const int px = (wvid * 4 + mt) * 16 + q4 * 4;
                    *(float4*)&qk[ml * QP + px] = *(float4*)&acc[mt][nt];
                }
            }
        }
    };

    float feat[8];
    #pragma unroll
    for (int d = 0; d < 8; ++d) feat[d] = 0.f;

    mfma_stage(0);
    __syncthreads();  // S_init: head 0 projections visible

    for (int h = 0; h < 8; ++h) {
        // ---- read projections + feat, elu1, row sums; write kf/av back ----
        float qf[8];
        float Sq = 0.f, tpart = 0.f;
        #pragma unroll
        for (int d = 0; d < 8; ++d) {
            const float aq = qk[d * QP + n]        + feat[d];
            const float ak = qk[(8 + d) * QP + n]  + feat[d];
            const float av = qk[(16 + d) * QP + n] + feat[d];
            qf[d] = aq > 0.f ? aq + 1.f : __expf(aq);
            const float kf = ak > 0.f ? ak + 1.f : __expf(ak);
            Sq    += qf[d];
            tpart += kf;
            qk[(8 + d) * QP + n]  = kf;   // own column: no cross-thread hazard
            qk[(16 + d) * QP + n] = av;
        }

        #pragma unroll
        for (int off = 1; off < 64; off <<= 1)
            tpart += __shfl_xor(tpart, off, 64);
        if (lane == 0) tp[h & 1][wvid] = tpart;

        __syncthreads();  // S2: kf/av/tp visible

        // ---- kv partials: thread (wvid, lane) -> (d'=lane>>3, c=lane&7) over 64 px ----
        {
            const float4* kr = (const float4*)(qk + (8 + (lane >> 3)) * QP + wvid * 64);
            const float4* vr = (const float4*)(qk + (16 + (lane & 7)) * QP + wvid * 64);
            float s0 = 0.f, s1 = 0.f, s2 = 0.f, s3 = 0.f;
            #pragma unroll
            for (int j = 0; j < 16; ++j) {
                const float4 kk = kr[j];
                const float4 vv = vr[j];
                s0 = fmaf(kk.x, vv.x, s0);
                s1 = fmaf(kk.y, vv.y, s1);
                s2 = fmaf(kk.z, vv.z, s2);
                s3 = fmaf(kk.w, vv.w, s3);
            }
            kvp[wvid * 64 + lane] = (s0 + s1) + (s2 + s3);
        }

        __syncthreads();  // S3: kvp visible; qk buffer now dead -> restage

        if (n < 64)
            kv_s[n] = (kvp[n] + kvp[64 + n]) + (kvp[128 + n] + kvp[192 + n]);

        if (h < 7)
            mfma_stage(h + 1);   // overlaps the n<64 reduce; writes qk for next head

        __syncthreads();  // S4: kv_s + next head's projections visible

        const float T  = ((tp[h & 1][0] + tp[h & 1][1]) + (tp[h & 1][2] + tp[h & 1][3])) + 8.0f * 1e-6f;
        const float zi = 1.0f / (Sq * T);

        float ft[8];
        #pragma unroll
        for (int d = 0; d < 8; ++d) ft[d] = 0.f;
        #pragma unroll
        for (int d = 0; d < 8; ++d) {
            const float qd = qf[d];
            const float4 a  = ((const float4*)(kv_s + d * 8))[0];
            const float4 bb = ((const float4*)(kv_s + d * 8))[1];
            ft[0] = fmaf(qd, a.x,  ft[0]);
            ft[1] = fmaf(qd, a.y,  ft[1]);
            ft[2] = fmaf(qd, a.z,  ft[2]);
            ft[3] = fmaf(qd, a.w,  ft[3]);
            ft[4] = fmaf(qd, bb.x, ft[4]);
            ft[5] = fmaf(qd, bb.y, ft[5]);
            ft[6] = fmaf(qd, bb.z, ft[6]);
            ft[7] = fmaf(qd, bb.w, ft[7]);
        }
        #pragma unroll
        for (int d = 0; d < 8; ++d) {
            feat[d] = ft[d] * zi;
            out[base + (h * 8 + d) * HW] = feat[d];
        }
    }
}

extern "C" void kernel_launch(void* const* d_in, const int* in_sizes, int n_in,
                              void* d_out, int out_size, void* d_ws, size_t ws_size,
                              hipStream_t stream) {
    const float* x  = (const float*)d_in[0];
    const float* w  = (const float*)d_in[1];
    float* out      = (float*)d_out;
    lwmsa_kernel<<<dim3(4096), dim3(256), 0, stream>>>(x, w, out);
}